// Round 5
// baseline (470.844 us; speedup 1.0000x reference)
//
#include <hip/hip_runtime.h>
#include <stdint.h>
#include <stddef.h>

// Problem constants
#define BROWS 8192
#define FEATK 7680
#define HIDN  512

typedef __attribute__((ext_vector_type(8))) __bf16 bf16x8;
typedef __attribute__((ext_vector_type(4))) float f32x4;

// fp32 -> bf16 round-to-nearest-even (bit manip; inputs finite)
__device__ __forceinline__ unsigned short f2b(float f) {
  unsigned int u = __float_as_uint(f);
  unsigned int r = (u + 0x7FFFu + ((u >> 16) & 1u)) >> 16;
  return (unsigned short)r;
}

// ---------------- K0: fused fp32 -> bf16 conversion of W1 and W2 (one launch) ----------------
__global__ void cvt2_kernel(const float* __restrict__ s1, unsigned short* __restrict__ d1, int n1,
                            const float* __restrict__ s2, unsigned short* __restrict__ d2, int n2) {
  int i = blockIdx.x * blockDim.x + threadIdx.x;
  int stride = gridDim.x * blockDim.x;
  for (; i < n1 + n2; i += stride) {
    const float4* sp; ushort4* dp; int j;
    if (i < n1) { sp = (const float4*)s1; dp = (ushort4*)d1; j = i; }
    else        { sp = (const float4*)s2; dp = (ushort4*)d2; j = i - n1; }
    float4 v = sp[j];
    ushort4 o;
    o.x = f2b(v.x); o.y = f2b(v.y); o.z = f2b(v.z); o.w = f2b(v.w);
    dp[j] = o;
  }
}

// ---------------- K1: fused fp32-A GEMM, split-K, counted-vmcnt pipeline ----------------
// P[kchunk] = A(fp32)[128-row stripe] @ W1B(bf16)^T over k-chunk. Full N=512 per block.
// BM=128, BN=512, BK=32. 512 threads = 8 waves; wave (wm,wn) computes 64x128 sub-tile.
// r5 theory: __syncthreads' implicit vmcnt(0) drained the prefetch every iter (fixed
// ~6500cy/iter regardless of bytes -> latency-serialized). Fix = T4 counted vmcnt:
// raw s_barrier + "s_waitcnt vmcnt(6)" so the 6 t+1 loads stay in flight ACROSS the
// barrier. Steady state: entry in-flight=4(B), issue 2A+4B ->10, vmcnt(6) retires
// exactly the previous B loads. Last iter: vmcnt(0). lgkmcnt(0) before barrier makes
// ds_writes visible and ds_reads retired before next-iter DMA overwrites the buffer.
#define K1_BM 128
#define K1_BK 32

__global__ __launch_bounds__(512, 1) void gemm1_fused_splitk(
    const float* __restrict__ A,            // [8192, 7680] fp32
    const unsigned short* __restrict__ Bm,  // [512, 7680] bf16
    float* __restrict__ P,                  // [S, 8192, 512] fp32 partials
    int M, int N, int K, int klen) {
  __shared__ unsigned short As[2][K1_BM * K1_BK];   // 2 x 8 KB
  __shared__ unsigned short Bs[2][HIDN * K1_BK];    // 2 x 32 KB

  const int tid  = threadIdx.x;
  const int lane = tid & 63;
  const int wid  = tid >> 6;          // 0..7
  const int wm   = wid >> 2;          // 0..1
  const int wn   = wid & 3;           // 0..3
  const int l16  = lane & 15;
  const int quad = lane >> 4;

  const int n       = blockIdx.x;     // 0..255
  const int kchunk  = n & 3;          // constant per XCD -> B chunk L2-resident
  const int rowblk  = n >> 2;         // 0..63

  const int rowBase = rowblk * K1_BM;
  const int k_begin = kchunk * klen;
  const int nsteps  = klen / K1_BK;   // 60

  // constant-per-thread staging indices
  const int arow  = tid >> 3;         // A rows: arow and 64+arow (8 float4 per 32-fp32 row)
  const int akq   = tid & 7;
  const int brow0 = (wid * 64 + lane) >> 2;   // B row per it: it*128 + brow0
  const int bkk   = (lane & 3) << 3;          // short offset within 32-short row

  f32x4 acc[4][8] = {};

  // ---- prologue: stage step 0 into buffer 0 (full drain, once) ----
  {
    const int k0 = k_begin;
#pragma unroll
    for (int it = 0; it < 2; ++it) {
      int row = it * 64 + arow;
      float4 v = *(const float4*)(A + (size_t)(rowBase + row) * K + k0 + akq * 4);
      ushort4 o;
      o.x = f2b(v.x); o.y = f2b(v.y); o.z = f2b(v.z); o.w = f2b(v.w);
      *(ushort4*)(&As[0][row * K1_BK + akq * 4]) = o;
    }
#pragma unroll
    for (int it = 0; it < 4; ++it) {
      int cb  = it * 512 + wid * 64;          // 16B-chunk base, wave-uniform
      int row = it * 128 + brow0;
      const unsigned short* gb = Bm + (size_t)row * K + (k0 + bkk);
      __builtin_amdgcn_global_load_lds(
          (const __attribute__((address_space(1))) void*)gb,
          (__attribute__((address_space(3))) void*)(&Bs[0][cb * 8]), 16, 0, 0);
    }
  }
  __syncthreads();

  int cur = 0;
  for (int t = 0; t < nsteps; ++t) {
    const int nxt = cur ^ 1;
    const bool hasNext = (t + 1 < nsteps);
    float4 va0, va1;

    // ---- issue stage(t+1); counted wait retires ONLY prev iter's B loads ----
    if (hasNext) {
      const int kn = k_begin + (t + 1) * K1_BK;
      va0 = *(const float4*)(A + (size_t)(rowBase + arow) * K + kn + akq * 4);
      va1 = *(const float4*)(A + (size_t)(rowBase + 64 + arow) * K + kn + akq * 4);
#pragma unroll
      for (int it = 0; it < 4; ++it) {
        int cb  = it * 512 + wid * 64;
        int row = it * 128 + brow0;
        const unsigned short* gb = Bm + (size_t)row * K + (kn + bkk);
        __builtin_amdgcn_global_load_lds(
            (const __attribute__((address_space(1))) void*)gb,
            (__attribute__((address_space(3))) void*)(&Bs[nxt][cb * 8]), 16, 0, 0);
      }
      asm volatile("s_waitcnt vmcnt(6)" ::: "memory");
    } else {
      asm volatile("s_waitcnt vmcnt(0)" ::: "memory");
    }

    // ---- compute on buffer cur (Bs[cur] loads now retired) ----
    bf16x8 af[4], bfr[8];
#pragma unroll
    for (int mt = 0; mt < 4; ++mt)
      af[mt] = *(const bf16x8*)(&As[cur][(wm * 64 + mt * 16 + l16) * K1_BK + quad * 8]);
#pragma unroll
    for (int nt = 0; nt < 8; ++nt)
      bfr[nt] = *(const bf16x8*)(&Bs[cur][(wn * 128 + nt * 16 + l16) * K1_BK + quad * 8]);
#pragma unroll
    for (int mt = 0; mt < 4; ++mt)
#pragma unroll
      for (int nt = 0; nt < 8; ++nt)
        acc[mt][nt] = __builtin_amdgcn_mfma_f32_16x16x32_bf16(af[mt], bfr[nt], acc[mt][nt], 0, 0, 0);

    // ---- late A-stage: compiler inserts the counted vmcnt for va0/va1 itself ----
    if (hasNext) {
      ushort4 o0, o1;
      o0.x = f2b(va0.x); o0.y = f2b(va0.y); o0.z = f2b(va0.z); o0.w = f2b(va0.w);
      o1.x = f2b(va1.x); o1.y = f2b(va1.y); o1.z = f2b(va1.z); o1.w = f2b(va1.w);
      *(ushort4*)(&As[nxt][arow * K1_BK + akq * 4]) = o0;
      *(ushort4*)(&As[nxt][(64 + arow) * K1_BK + akq * 4]) = o1;
    }
    // ds_writes visible + ds_reads retired; B loads for nxt stay in flight across barrier
    asm volatile("s_waitcnt lgkmcnt(0)" ::: "memory");
    __builtin_amdgcn_s_barrier();
    cur = nxt;
  }

  // ---- epilogue: fp32 partials (plane = kchunk) ----
  float* outp = P + (size_t)kchunk * M * N;
#pragma unroll
  for (int mt = 0; mt < 4; ++mt) {
#pragma unroll
    for (int r = 0; r < 4; ++r) {
      int row = rowBase + wm * 64 + mt * 16 + quad * 4 + r;
      float* cp = outp + (size_t)row * N + wn * 128 + l16;
#pragma unroll
      for (int nt = 0; nt < 8; ++nt) cp[nt * 16] = acc[mt][nt][r];
    }
  }
}

// Reduce S=4 partials + bias + ReLU -> bf16
__global__ __launch_bounds__(256) void reduce4_bias_relu(
    const float* __restrict__ P, const float* __restrict__ bias,
    unsigned short* __restrict__ H, int MN4, int N4) {
  int i = blockIdx.x * blockDim.x + threadIdx.x;
  if (i >= MN4) return;
  const float4* p = (const float4*)P;
  float4 a = p[i];
  float4 b = p[i + MN4];
  float4 c = p[i + 2 * MN4];
  float4 d = p[i + 3 * MN4];
  float4 bs = ((const float4*)bias)[i % N4];
  ushort4 o;
  o.x = f2b(fmaxf(a.x + b.x + c.x + d.x + bs.x, 0.0f));
  o.y = f2b(fmaxf(a.y + b.y + c.y + d.y + bs.y, 0.0f));
  o.z = f2b(fmaxf(a.z + b.z + c.z + d.z + bs.z, 0.0f));
  o.w = f2b(fmaxf(a.w + b.w + c.w + d.w + bs.w, 0.0f));
  ((ushort4*)H)[i] = o;
}

// ---------------- K2: bf16 GEMM C = relu(A @ B^T + bias), counted-vmcnt pipeline ----------------
// M=8192 N=512 K=512: 512 blocks (2/CU), 8 K-steps. Same T4 fix: 6 loads/iter in flight
// across the barrier; vmcnt(6) retires only the previous iteration's 6.
#define K2_BM 64
#define K2_BN 128
#define K2_BK 64

__global__ __launch_bounds__(256, 2) void gemm2_bias_relu(
    const unsigned short* __restrict__ A,   // [8192,512] bf16
    const unsigned short* __restrict__ Bm,  // [512,512] bf16
    const float* __restrict__ bias,
    unsigned short* __restrict__ C,         // [8192,512] bf16
    int M, int N, int K) {
  __shared__ unsigned short As[2][K2_BM * K2_BK];  // 2 x 8 KB
  __shared__ unsigned short Bs[2][K2_BN * K2_BK];  // 2 x 16 KB
  const int tid  = threadIdx.x;
  const int lane = tid & 63;
  const int wid  = tid >> 6;
  const int wm   = wid >> 1;   // 0..1
  const int wn   = wid & 1;    // 0..1
  const int l16  = lane & 15;
  const int quad = lane >> 4;
  const int rowBase = blockIdx.y * K2_BM;
  const int colBase = blockIdx.x * K2_BN;

  const int srow = tid >> 3;          // per it: row = it*32 + srow
  const int skk  = (tid & 7) << 3;    // short offset within 64-short row

  f32x4 acc[2][4] = {};
  const int nsteps = K / K2_BK;       // 8

  // prologue: stage step 0 (full drain, once)
#pragma unroll
  for (int it = 0; it < 2; ++it) {    // A: 64 rows x 8 chunks = 512 chunks
    int cb  = it * 256 + wid * 64;
    int row = it * 32 + srow;
    const unsigned short* ga = A + (size_t)(rowBase + row) * K + skk;
    __builtin_amdgcn_global_load_lds(
        (const __attribute__((address_space(1))) void*)ga,
        (__attribute__((address_space(3))) void*)(&As[0][cb * 8]), 16, 0, 0);
  }
#pragma unroll
  for (int it = 0; it < 4; ++it) {    // B: 128 rows x 8 chunks = 1024 chunks
    int cb  = it * 256 + wid * 64;
    int row = it * 32 + srow;
    const unsigned short* gb = Bm + (size_t)(colBase + row) * K + skk;
    __builtin_amdgcn_global_load_lds(
        (const __attribute__((address_space(1))) void*)gb,
        (__attribute__((address_space(3))) void*)(&Bs[0][cb * 8]), 16, 0, 0);
  }
  __syncthreads();

  int cur = 0;
  for (int t = 0; t < nsteps; ++t) {
    const int nxt = cur ^ 1;
    if (t + 1 < nsteps) {
      const int kn = (t + 1) * K2_BK;
#pragma unroll
      for (int it = 0; it < 2; ++it) {
        int cb  = it * 256 + wid * 64;
        int row = it * 32 + srow;
        const unsigned short* ga = A + (size_t)(rowBase + row) * K + kn + skk;
        __builtin_amdgcn_global_load_lds(
            (const __attribute__((address_space(1))) void*)ga,
            (__attribute__((address_space(3))) void*)(&As[nxt][cb * 8]), 16, 0, 0);
      }
#pragma unroll
      for (int it = 0; it < 4; ++it) {
        int cb  = it * 256 + wid * 64;
        int row = it * 32 + srow;
        const unsigned short* gb = Bm + (size_t)(colBase + row) * K + kn + skk;
        __builtin_amdgcn_global_load_lds(
            (const __attribute__((address_space(1))) void*)gb,
            (__attribute__((address_space(3))) void*)(&Bs[nxt][cb * 8]), 16, 0, 0);
      }
      asm volatile("s_waitcnt vmcnt(6)" ::: "memory");
    } else {
      asm volatile("s_waitcnt vmcnt(0)" ::: "memory");
    }
#pragma unroll
    for (int kk = 0; kk < K2_BK; kk += 32) {
      bf16x8 af[2], bfr[4];
#pragma unroll
      for (int mt = 0; mt < 2; ++mt)
        af[mt] = *(const bf16x8*)(&As[cur][(wm * 32 + mt * 16 + l16) * K2_BK + kk + quad * 8]);
#pragma unroll
      for (int nt = 0; nt < 4; ++nt)
        bfr[nt] = *(const bf16x8*)(&Bs[cur][(wn * 64 + nt * 16 + l16) * K2_BK + kk + quad * 8]);
#pragma unroll
      for (int mt = 0; mt < 2; ++mt)
#pragma unroll
        for (int nt = 0; nt < 4; ++nt)
          acc[mt][nt] = __builtin_amdgcn_mfma_f32_16x16x32_bf16(af[mt], bfr[nt], acc[mt][nt], 0, 0, 0);
    }
    asm volatile("s_waitcnt lgkmcnt(0)" ::: "memory");
    __builtin_amdgcn_s_barrier();
    cur = nxt;
  }

  float bvals[4];
#pragma unroll
  for (int nt = 0; nt < 4; ++nt) bvals[nt] = bias[colBase + wn * 64 + nt * 16 + l16];
#pragma unroll
  for (int mt = 0; mt < 2; ++mt) {
#pragma unroll
    for (int r = 0; r < 4; ++r) {
      int row = rowBase + wm * 32 + mt * 16 + quad * 4 + r;
      unsigned short* cp = C + (size_t)row * N + colBase + wn * 64 + l16;
#pragma unroll
      for (int nt = 0; nt < 4; ++nt) {
        float v = fmaxf(acc[mt][nt][r] + bvals[nt], 0.0f);
        cp[nt * 16] = f2b(v);
      }
    }
  }
}

// ---------------- K3: GEMM3 (512->4) + per-scene routed 2x2 affines ----------------
__global__ __launch_bounds__(256) void head_kernel(
    const unsigned short* __restrict__ h2,  // [B,512] bf16
    const float* __restrict__ W3,           // [4,512]
    const float* __restrict__ b3,           // [4]
    const int* __restrict__ sidx,           // [B] int32
    const float* __restrict__ xyW,          // [72,2,2]
    const float* __restrict__ xyb,          // [72,2]
    const float* __restrict__ tW,           // [72,2,2]
    float* __restrict__ out) {              // [B,4]
  int wave = (blockIdx.x * blockDim.x + threadIdx.x) >> 6;
  int lane = threadIdx.x & 63;
  if (wave >= BROWS) return;

  bf16x8 hv = *(const bf16x8*)(h2 + (size_t)wave * 512 + lane * 8);
  float hf[8];
#pragma unroll
  for (int j = 0; j < 8; ++j) hf[j] = (float)hv[j];

  float s[4];
#pragma unroll
  for (int o = 0; o < 4; ++o) {
    const float* wrow = W3 + o * 512 + lane * 8;
    float4 w0 = ((const float4*)wrow)[0];
    float4 w1 = ((const float4*)wrow)[1];
    float a = hf[0] * w0.x + hf[1] * w0.y + hf[2] * w0.z + hf[3] * w0.w +
              hf[4] * w1.x + hf[5] * w1.y + hf[6] * w1.z + hf[7] * w1.w;
#pragma unroll
    for (int off = 32; off > 0; off >>= 1) a += __shfl_down(a, off, 64);
    s[o] = a;
  }

  if (lane == 0) {
#pragma unroll
    for (int o = 0; o < 4; ++o) s[o] += b3[o];
    int sc = sidx[wave];
    const float* wx = xyW + sc * 4;
    const float* bx = xyb + sc * 2;
    const float* wt = tW + sc * 4;
    float o0 = wx[0] * s[0] + wx[1] * s[1] + bx[0];
    float o1 = wx[2] * s[0] + wx[3] * s[1] + bx[1];
    float o2 = wt[0] * s[2] + wt[1] * s[3];
    float o3 = wt[2] * s[2] + wt[3] * s[3];
    ((float4*)out)[wave] = make_float4(o0, o1, o2, o3);
  }
}

// ---------------- workspace layout (bytes) ----------------
#define WS_W1B   0UL                      // 512*7680*2  = 7864320
#define WS_W2B   7864320UL                // + 512*512*2 = 524288
#define WS_H1    8388608UL                // + 8192*512*2
#define WS_H2    16777216UL               // + 8192*512*2
#define WS_PART  25165824UL               // + 4*8192*512*4 = 67108864
#define WS_NEED  92274688UL

extern "C" void kernel_launch(void* const* d_in, const int* in_sizes, int n_in,
                              void* d_out, int out_size, void* d_ws, size_t ws_size,
                              hipStream_t stream) {
  const float* feat = (const float*)d_in[0];
  const int*   sidx = (const int*)d_in[1];
  const float* W1   = (const float*)d_in[2];
  const float* b1   = (const float*)d_in[3];
  const float* W2   = (const float*)d_in[4];
  const float* b2   = (const float*)d_in[5];
  const float* W3   = (const float*)d_in[6];
  const float* b3   = (const float*)d_in[7];
  const float* xyW  = (const float*)d_in[8];
  const float* xyb  = (const float*)d_in[9];
  const float* tW   = (const float*)d_in[10];
  float* out = (float*)d_out;

  if (ws_size < WS_NEED) return;  // ws observed ~1 GB; guard only

  char* ws = (char*)d_ws;
  unsigned short* W1B  = (unsigned short*)(ws + WS_W1B);
  unsigned short* W2B  = (unsigned short*)(ws + WS_W2B);
  unsigned short* h1   = (unsigned short*)(ws + WS_H1);
  unsigned short* h2   = (unsigned short*)(ws + WS_H2);
  float*          part = (float*)(ws + WS_PART);

  // K0: convert W1 and W2 fp32 -> bf16 in ONE launch
  cvt2_kernel<<<576, 256, 0, stream>>>(W1, W1B, (HIDN * FEATK) / 4,
                                       W2, W2B, (HIDN * HIDN) / 4);

  // K1: partials = feat @ W1^T (split-K S=4, BM=128, 256 blocks, counted-vmcnt)
  gemm1_fused_splitk<<<256, 512, 0, stream>>>(
      feat, W1B, part, BROWS, HIDN, FEATK, FEATK / 4);
  reduce4_bias_relu<<<(BROWS * HIDN / 4 + 255) / 256, 256, 0, stream>>>(
      part, b1, h1, BROWS * HIDN / 4, HIDN / 4);

  // K2: h2 = relu(h1 @ W2^T + b2)  (BM=64 BN=128 -> 512 blocks, counted-vmcnt)
  gemm2_bias_relu<<<dim3(HIDN / K2_BN, BROWS / K2_BM), 256, 0, stream>>>(
      h1, W2B, b2, h2, BROWS, HIDN, HIDN);

  // K3: shared = h2 @ W3^T + b3 ; routed 2x2 affines -> out
  head_kernel<<<(BROWS * 64) / 256, 256, 0, stream>>>(
      h2, W3, b3, sidx, xyW, xyb, tW, out);
}

// Round 6
// 456.554 us; speedup vs baseline: 1.0313x; 1.0313x over previous
//
#include <hip/hip_runtime.h>
#include <stdint.h>
#include <stddef.h>

// Problem constants
#define BROWS 8192
#define FEATK 7680
#define HIDN  512

typedef __attribute__((ext_vector_type(8))) __bf16 bf16x8;
typedef __attribute__((ext_vector_type(4))) float f32x4;

// fp32 -> bf16 round-to-nearest-even (bit manip; inputs finite)
__device__ __forceinline__ unsigned short f2b(float f) {
  unsigned int u = __float_as_uint(f);
  unsigned int r = (u + 0x7FFFu + ((u >> 16) & 1u)) >> 16;
  return (unsigned short)r;
}

// ---------------- K0: fused fp32 -> bf16 conversion of W1 and W2 (one launch) ----------------
__global__ void cvt2_kernel(const float* __restrict__ s1, unsigned short* __restrict__ d1, int n1,
                            const float* __restrict__ s2, unsigned short* __restrict__ d2, int n2) {
  int i = blockIdx.x * blockDim.x + threadIdx.x;
  int stride = gridDim.x * blockDim.x;
  for (; i < n1 + n2; i += stride) {
    const float4* sp; ushort4* dp; int j;
    if (i < n1) { sp = (const float4*)s1; dp = (ushort4*)d1; j = i; }
    else        { sp = (const float4*)s2; dp = (ushort4*)d2; j = i - n1; }
    float4 v = sp[j];
    ushort4 o;
    o.x = f2b(v.x); o.y = f2b(v.y); o.z = f2b(v.z); o.w = f2b(v.w);
    dp[j] = o;
  }
}

// ---------------- K1: fused fp32-A GEMM, split-K, 4-phase interleaved schedule ----------------
// P[kchunk] = A(fp32)[128-row stripe] @ W1B(bf16)^T. BM=128, BN=512, BK=32, 512 thr = 8 waves.
// r6: T3+T4+T5 combo (guide m218: counted-vmcnt on 1-phase = null, confirmed r5; gain gates
// on phase structure). Per K-step, 4 phases: {ds_read subtile | issue stage loads -> bar ->
// lgkm(0) -> setprio(1) -> 8 MFMA -> setprio(0) -> bar}. B: 3-deep circular LDS buffers,
// 2-step-ahead prefetch; vmcnt(4) at P3 retires exactly {A(t+1), B(t+1)}, keeps B(t+2)'s 4
// loads in flight across the step boundary (never drains to 0 mid-loop). A: reg-staged
// (fp32->bf16 cvt), issued P0, written P3 before lgkm(0)+barrier (cross-wave visibility).
#define K1_BM 128
#define K1_BK 32

#define K1_BDMA(buf, kcol, it)                                                   \
  do {                                                                           \
    int cb_  = (it) * 512 + wid * 64;                                            \
    int row_ = (it) * 128 + brow0;                                               \
    const unsigned short* gb_ = Bm + (size_t)row_ * K + ((kcol) + bkk);          \
    __builtin_amdgcn_global_load_lds(                                            \
        (const __attribute__((address_space(1))) void*)gb_,                      \
        (__attribute__((address_space(3))) void*)(&Bs[buf][cb_ * 8]), 16, 0, 0); \
  } while (0)

__global__ __launch_bounds__(512, 1) void gemm1_fused_splitk(
    const float* __restrict__ A,            // [8192, 7680] fp32
    const unsigned short* __restrict__ Bm,  // [512, 7680] bf16
    float* __restrict__ P,                  // [S, 8192, 512] fp32 partials
    int M, int N, int K, int klen) {
  __shared__ unsigned short As[2][K1_BM * K1_BK];   // 2 x 8 KB
  __shared__ unsigned short Bs[3][HIDN * K1_BK];    // 3 x 32 KB (circular)

  const int tid  = threadIdx.x;
  const int lane = tid & 63;
  const int wid  = tid >> 6;          // 0..7
  const int wm   = wid >> 2;          // 0..1
  const int wn   = wid & 3;           // 0..3
  const int l16  = lane & 15;
  const int quad = lane >> 4;

  const int n       = blockIdx.x;     // 0..255
  const int kchunk  = n & 3;          // XCD-pinned k-chunk (B L2-resident)
  const int rowblk  = n >> 2;         // 0..63
  const int rowBase = rowblk * K1_BM;
  const int k_begin = kchunk * klen;
  const int nsteps  = klen / K1_BK;   // 60 (>= 3)

  const int arow  = tid >> 3;         // A rows: arow and 64+arow
  const int akq   = tid & 7;
  const int brow0 = (wid * 64 + lane) >> 2;
  const int bkk   = (lane & 3) << 3;

  f32x4 acc[4][8] = {};

  // ---- prologue: A(0) regs; B(0), B(1) DMA; cvt+write As[0]; retire B(0) ----
  {
    float4 va0 = *(const float4*)(A + (size_t)(rowBase + arow) * K + k_begin + akq * 4);
    float4 va1 = *(const float4*)(A + (size_t)(rowBase + 64 + arow) * K + k_begin + akq * 4);
    K1_BDMA(0, k_begin, 0); K1_BDMA(0, k_begin, 1); K1_BDMA(0, k_begin, 2); K1_BDMA(0, k_begin, 3);
    const int k1c = k_begin + K1_BK;
    K1_BDMA(1, k1c, 0); K1_BDMA(1, k1c, 1); K1_BDMA(1, k1c, 2); K1_BDMA(1, k1c, 3);
    asm volatile("s_waitcnt vmcnt(8)" ::: "memory");   // retire the 2 A loads
    ushort4 o0, o1;
    o0.x = f2b(va0.x); o0.y = f2b(va0.y); o0.z = f2b(va0.z); o0.w = f2b(va0.w);
    o1.x = f2b(va1.x); o1.y = f2b(va1.y); o1.z = f2b(va1.z); o1.w = f2b(va1.w);
    *(ushort4*)(&As[0][arow * K1_BK + akq * 4]) = o0;
    *(ushort4*)(&As[0][(64 + arow) * K1_BK + akq * 4]) = o1;
    asm volatile("s_waitcnt vmcnt(4) lgkmcnt(0)" ::: "memory");  // retire B(0); writes visible
    __builtin_amdgcn_s_barrier();
  }

  int cur3 = 0, b2 = 2, curA = 0;
  for (int t = 0; t < nsteps; ++t) {
    const bool hasNext = (t + 1 < nsteps);
    const bool hasB2   = (t + 2 < nsteps);
    const int  nxtA    = curA ^ 1;
    const int  kn      = k_begin + (t + 1) * K1_BK;
    const int  kn2     = k_begin + (t + 2) * K1_BK;
    float4 va0, va1;
    bf16x8 af[4], bfr[8];

    // ================= P0: af + bfr01 reads; issue A(t+1) =================
#pragma unroll
    for (int mt = 0; mt < 4; ++mt)
      af[mt] = *(const bf16x8*)(&As[curA][(wm * 64 + mt * 16 + l16) * K1_BK + quad * 8]);
    bfr[0] = *(const bf16x8*)(&Bs[cur3][(wn * 128 + 0 * 16 + l16) * K1_BK + quad * 8]);
    bfr[1] = *(const bf16x8*)(&Bs[cur3][(wn * 128 + 1 * 16 + l16) * K1_BK + quad * 8]);
    if (hasNext) {
      va0 = *(const float4*)(A + (size_t)(rowBase + arow) * K + kn + akq * 4);
      va1 = *(const float4*)(A + (size_t)(rowBase + 64 + arow) * K + kn + akq * 4);
    }
    __builtin_amdgcn_s_barrier();
    asm volatile("s_waitcnt lgkmcnt(0)" ::: "memory");
    __builtin_amdgcn_s_setprio(1);
#pragma unroll
    for (int mt = 0; mt < 4; ++mt) {
      acc[mt][0] = __builtin_amdgcn_mfma_f32_16x16x32_bf16(af[mt], bfr[0], acc[mt][0], 0, 0, 0);
      acc[mt][1] = __builtin_amdgcn_mfma_f32_16x16x32_bf16(af[mt], bfr[1], acc[mt][1], 0, 0, 0);
    }
    __builtin_amdgcn_s_setprio(0);
    __builtin_amdgcn_s_barrier();

    // ================= P1: bfr23; issue B(t+2) chunks 0,1 =================
    bfr[2] = *(const bf16x8*)(&Bs[cur3][(wn * 128 + 2 * 16 + l16) * K1_BK + quad * 8]);
    bfr[3] = *(const bf16x8*)(&Bs[cur3][(wn * 128 + 3 * 16 + l16) * K1_BK + quad * 8]);
    if (hasB2) { K1_BDMA(b2, kn2, 0); K1_BDMA(b2, kn2, 1); }
    __builtin_amdgcn_s_barrier();
    asm volatile("s_waitcnt lgkmcnt(0)" ::: "memory");
    __builtin_amdgcn_s_setprio(1);
#pragma unroll
    for (int mt = 0; mt < 4; ++mt) {
      acc[mt][2] = __builtin_amdgcn_mfma_f32_16x16x32_bf16(af[mt], bfr[2], acc[mt][2], 0, 0, 0);
      acc[mt][3] = __builtin_amdgcn_mfma_f32_16x16x32_bf16(af[mt], bfr[3], acc[mt][3], 0, 0, 0);
    }
    __builtin_amdgcn_s_setprio(0);
    __builtin_amdgcn_s_barrier();

    // ================= P2: bfr45; issue B(t+2) chunk 2 =================
    bfr[4] = *(const bf16x8*)(&Bs[cur3][(wn * 128 + 4 * 16 + l16) * K1_BK + quad * 8]);
    bfr[5] = *(const bf16x8*)(&Bs[cur3][(wn * 128 + 5 * 16 + l16) * K1_BK + quad * 8]);
    if (hasB2) { K1_BDMA(b2, kn2, 2); }
    __builtin_amdgcn_s_barrier();
    asm volatile("s_waitcnt lgkmcnt(0)" ::: "memory");
    __builtin_amdgcn_s_setprio(1);
#pragma unroll
    for (int mt = 0; mt < 4; ++mt) {
      acc[mt][4] = __builtin_amdgcn_mfma_f32_16x16x32_bf16(af[mt], bfr[4], acc[mt][4], 0, 0, 0);
      acc[mt][5] = __builtin_amdgcn_mfma_f32_16x16x32_bf16(af[mt], bfr[5], acc[mt][5], 0, 0, 0);
    }
    __builtin_amdgcn_s_setprio(0);
    __builtin_amdgcn_s_barrier();

    // ===== P3: bfr67; issue B(t+2) chunk 3; vmcnt(4) retires A(t+1)+B(t+1); cvt+write =====
    bfr[6] = *(const bf16x8*)(&Bs[cur3][(wn * 128 + 6 * 16 + l16) * K1_BK + quad * 8]);
    bfr[7] = *(const bf16x8*)(&Bs[cur3][(wn * 128 + 7 * 16 + l16) * K1_BK + quad * 8]);
    if (hasB2) { K1_BDMA(b2, kn2, 3); }
    if (hasNext) {
      if (hasB2) { asm volatile("s_waitcnt vmcnt(4)" ::: "memory"); }
      else       { asm volatile("s_waitcnt vmcnt(0)" ::: "memory"); }
      ushort4 o0, o1;
      o0.x = f2b(va0.x); o0.y = f2b(va0.y); o0.z = f2b(va0.z); o0.w = f2b(va0.w);
      o1.x = f2b(va1.x); o1.y = f2b(va1.y); o1.z = f2b(va1.z); o1.w = f2b(va1.w);
      *(ushort4*)(&As[nxtA][arow * K1_BK + akq * 4]) = o0;
      *(ushort4*)(&As[nxtA][(64 + arow) * K1_BK + akq * 4]) = o1;
    }
    asm volatile("s_waitcnt lgkmcnt(0)" ::: "memory");  // ds_write visible before barrier
    __builtin_amdgcn_s_barrier();
    __builtin_amdgcn_s_setprio(1);
#pragma unroll
    for (int mt = 0; mt < 4; ++mt) {
      acc[mt][6] = __builtin_amdgcn_mfma_f32_16x16x32_bf16(af[mt], bfr[6], acc[mt][6], 0, 0, 0);
      acc[mt][7] = __builtin_amdgcn_mfma_f32_16x16x32_bf16(af[mt], bfr[7], acc[mt][7], 0, 0, 0);
    }
    __builtin_amdgcn_s_setprio(0);
    __builtin_amdgcn_s_barrier();

    curA = nxtA;
    cur3 = (cur3 == 2) ? 0 : cur3 + 1;
    b2   = (b2 == 2) ? 0 : b2 + 1;
  }

  // ---- epilogue: fp32 partials (plane = kchunk) ----
  float* outp = P + (size_t)kchunk * M * N;
#pragma unroll
  for (int mt = 0; mt < 4; ++mt) {
#pragma unroll
    for (int r = 0; r < 4; ++r) {
      int row = rowBase + wm * 64 + mt * 16 + quad * 4 + r;
      float* cp = outp + (size_t)row * N + wn * 128 + l16;
#pragma unroll
      for (int nt = 0; nt < 8; ++nt) cp[nt * 16] = acc[mt][nt][r];
    }
  }
}

// Reduce S=4 partials + bias + ReLU -> bf16
__global__ __launch_bounds__(256) void reduce4_bias_relu(
    const float* __restrict__ P, const float* __restrict__ bias,
    unsigned short* __restrict__ H, int MN4, int N4) {
  int i = blockIdx.x * blockDim.x + threadIdx.x;
  if (i >= MN4) return;
  const float4* p = (const float4*)P;
  float4 a = p[i];
  float4 b = p[i + MN4];
  float4 c = p[i + 2 * MN4];
  float4 d = p[i + 3 * MN4];
  float4 bs = ((const float4*)bias)[i % N4];
  ushort4 o;
  o.x = f2b(fmaxf(a.x + b.x + c.x + d.x + bs.x, 0.0f));
  o.y = f2b(fmaxf(a.y + b.y + c.y + d.y + bs.y, 0.0f));
  o.z = f2b(fmaxf(a.z + b.z + c.z + d.z + bs.z, 0.0f));
  o.w = f2b(fmaxf(a.w + b.w + c.w + d.w + bs.w, 0.0f));
  ((ushort4*)H)[i] = o;
}

// ---------------- K2: bf16 GEMM C = relu(A @ B^T + bias), counted-vmcnt (r5, passing) ----------------
#define K2_BM 64
#define K2_BN 128
#define K2_BK 64

__global__ __launch_bounds__(256, 2) void gemm2_bias_relu(
    const unsigned short* __restrict__ A,   // [8192,512] bf16
    const unsigned short* __restrict__ Bm,  // [512,512] bf16
    const float* __restrict__ bias,
    unsigned short* __restrict__ C,         // [8192,512] bf16
    int M, int N, int K) {
  __shared__ unsigned short As[2][K2_BM * K2_BK];  // 2 x 8 KB
  __shared__ unsigned short Bs[2][K2_BN * K2_BK];  // 2 x 16 KB
  const int tid  = threadIdx.x;
  const int lane = tid & 63;
  const int wid  = tid >> 6;
  const int wm   = wid >> 1;   // 0..1
  const int wn   = wid & 1;    // 0..1
  const int l16  = lane & 15;
  const int quad = lane >> 4;
  const int rowBase = blockIdx.y * K2_BM;
  const int colBase = blockIdx.x * K2_BN;

  const int srow = tid >> 3;          // per it: row = it*32 + srow
  const int skk  = (tid & 7) << 3;    // short offset within 64-short row

  f32x4 acc[2][4] = {};
  const int nsteps = K / K2_BK;       // 8

#pragma unroll
  for (int it = 0; it < 2; ++it) {
    int cb  = it * 256 + wid * 64;
    int row = it * 32 + srow;
    const unsigned short* ga = A + (size_t)(rowBase + row) * K + skk;
    __builtin_amdgcn_global_load_lds(
        (const __attribute__((address_space(1))) void*)ga,
        (__attribute__((address_space(3))) void*)(&As[0][cb * 8]), 16, 0, 0);
  }
#pragma unroll
  for (int it = 0; it < 4; ++it) {
    int cb  = it * 256 + wid * 64;
    int row = it * 32 + srow;
    const unsigned short* gb = Bm + (size_t)(colBase + row) * K + skk;
    __builtin_amdgcn_global_load_lds(
        (const __attribute__((address_space(1))) void*)gb,
        (__attribute__((address_space(3))) void*)(&Bs[0][cb * 8]), 16, 0, 0);
  }
  __syncthreads();

  int cur = 0;
  for (int t = 0; t < nsteps; ++t) {
    const int nxt = cur ^ 1;
    if (t + 1 < nsteps) {
      const int kn = (t + 1) * K2_BK;
#pragma unroll
      for (int it = 0; it < 2; ++it) {
        int cb  = it * 256 + wid * 64;
        int row = it * 32 + srow;
        const unsigned short* ga = A + (size_t)(rowBase + row) * K + kn + skk;
        __builtin_amdgcn_global_load_lds(
            (const __attribute__((address_space(1))) void*)ga,
            (__attribute__((address_space(3))) void*)(&As[nxt][cb * 8]), 16, 0, 0);
      }
#pragma unroll
      for (int it = 0; it < 4; ++it) {
        int cb  = it * 256 + wid * 64;
        int row = it * 32 + srow;
        const unsigned short* gb = Bm + (size_t)(colBase + row) * K + kn + skk;
        __builtin_amdgcn_global_load_lds(
            (const __attribute__((address_space(1))) void*)gb,
            (__attribute__((address_space(3))) void*)(&Bs[nxt][cb * 8]), 16, 0, 0);
      }
      asm volatile("s_waitcnt vmcnt(6)" ::: "memory");
    } else {
      asm volatile("s_waitcnt vmcnt(0)" ::: "memory");
    }
#pragma unroll
    for (int kk = 0; kk < K2_BK; kk += 32) {
      bf16x8 af[2], bfr[4];
#pragma unroll
      for (int mt = 0; mt < 2; ++mt)
        af[mt] = *(const bf16x8*)(&As[cur][(wm * 32 + mt * 16 + l16) * K2_BK + kk + quad * 8]);
#pragma unroll
      for (int nt = 0; nt < 4; ++nt)
        bfr[nt] = *(const bf16x8*)(&Bs[cur][(wn * 64 + nt * 16 + l16) * K2_BK + kk + quad * 8]);
#pragma unroll
      for (int mt = 0; mt < 2; ++mt)
#pragma unroll
        for (int nt = 0; nt < 4; ++nt)
          acc[mt][nt] = __builtin_amdgcn_mfma_f32_16x16x32_bf16(af[mt], bfr[nt], acc[mt][nt], 0, 0, 0);
    }
    asm volatile("s_waitcnt lgkmcnt(0)" ::: "memory");
    __builtin_amdgcn_s_barrier();
    cur = nxt;
  }

  float bvals[4];
#pragma unroll
  for (int nt = 0; nt < 4; ++nt) bvals[nt] = bias[colBase + wn * 64 + nt * 16 + l16];
#pragma unroll
  for (int mt = 0; mt < 2; ++mt) {
#pragma unroll
    for (int r = 0; r < 4; ++r) {
      int row = rowBase + wm * 32 + mt * 16 + quad * 4 + r;
      unsigned short* cp = C + (size_t)row * N + colBase + wn * 64 + l16;
#pragma unroll
      for (int nt = 0; nt < 4; ++nt) {
        float v = fmaxf(acc[mt][nt][r] + bvals[nt], 0.0f);
        cp[nt * 16] = f2b(v);
      }
    }
  }
}

// ---------------- K3: GEMM3 (512->4) + per-scene routed 2x2 affines ----------------
__global__ __launch_bounds__(256) void head_kernel(
    const unsigned short* __restrict__ h2,  // [B,512] bf16
    const float* __restrict__ W3,           // [4,512]
    const float* __restrict__ b3,           // [4]
    const int* __restrict__ sidx,           // [B] int32
    const float* __restrict__ xyW,          // [72,2,2]
    const float* __restrict__ xyb,          // [72,2]
    const float* __restrict__ tW,           // [72,2,2]
    float* __restrict__ out) {              // [B,4]
  int wave = (blockIdx.x * blockDim.x + threadIdx.x) >> 6;
  int lane = threadIdx.x & 63;
  if (wave >= BROWS) return;

  bf16x8 hv = *(const bf16x8*)(h2 + (size_t)wave * 512 + lane * 8);
  float hf[8];
#pragma unroll
  for (int j = 0; j < 8; ++j) hf[j] = (float)hv[j];

  float s[4];
#pragma unroll
  for (int o = 0; o < 4; ++o) {
    const float* wrow = W3 + o * 512 + lane * 8;
    float4 w0 = ((const float4*)wrow)[0];
    float4 w1 = ((const float4*)wrow)[1];
    float a = hf[0] * w0.x + hf[1] * w0.y + hf[2] * w0.z + hf[3] * w0.w +
              hf[4] * w1.x + hf[5] * w1.y + hf[6] * w1.z + hf[7] * w1.w;
#pragma unroll
    for (int off = 32; off > 0; off >>= 1) a += __shfl_down(a, off, 64);
    s[o] = a;
  }

  if (lane == 0) {
#pragma unroll
    for (int o = 0; o < 4; ++o) s[o] += b3[o];
    int sc = sidx[wave];
    const float* wx = xyW + sc * 4;
    const float* bx = xyb + sc * 2;
    const float* wt = tW + sc * 4;
    float o0 = wx[0] * s[0] + wx[1] * s[1] + bx[0];
    float o1 = wx[2] * s[0] + wx[3] * s[1] + bx[1];
    float o2 = wt[0] * s[2] + wt[1] * s[3];
    float o3 = wt[2] * s[2] + wt[3] * s[3];
    ((float4*)out)[wave] = make_float4(o0, o1, o2, o3);
  }
}

// ---------------- workspace layout (bytes) ----------------
#define WS_W1B   0UL                      // 512*7680*2  = 7864320
#define WS_W2B   7864320UL                // + 512*512*2 = 524288
#define WS_H1    8388608UL                // + 8192*512*2
#define WS_H2    16777216UL               // + 8192*512*2
#define WS_PART  25165824UL               // + 4*8192*512*4 = 67108864
#define WS_NEED  92274688UL

extern "C" void kernel_launch(void* const* d_in, const int* in_sizes, int n_in,
                              void* d_out, int out_size, void* d_ws, size_t ws_size,
                              hipStream_t stream) {
  const float* feat = (const float*)d_in[0];
  const int*   sidx = (const int*)d_in[1];
  const float* W1   = (const float*)d_in[2];
  const float* b1   = (const float*)d_in[3];
  const float* W2   = (const float*)d_in[4];
  const float* b2   = (const float*)d_in[5];
  const float* W3   = (const float*)d_in[6];
  const float* b3   = (const float*)d_in[7];
  const float* xyW  = (const float*)d_in[8];
  const float* xyb  = (const float*)d_in[9];
  const float* tW   = (const float*)d_in[10];
  float* out = (float*)d_out;

  if (ws_size < WS_NEED) return;  // ws observed ~1 GB; guard only

  char* ws = (char*)d_ws;
  unsigned short* W1B  = (unsigned short*)(ws + WS_W1B);
  unsigned short* W2B  = (unsigned short*)(ws + WS_W2B);
  unsigned short* h1   = (unsigned short*)(ws + WS_H1);
  unsigned short* h2   = (unsigned short*)(ws + WS_H2);
  float*          part = (float*)(ws + WS_PART);

  // K0: convert W1 and W2 fp32 -> bf16 in ONE launch
  cvt2_kernel<<<576, 256, 0, stream>>>(W1, W1B, (HIDN * FEATK) / 4,
                                       W2, W2B, (HIDN * HIDN) / 4);

  // K1: partials = feat @ W1^T (split-K S=4, BM=128, 4-phase interleaved, 3-deep B)
  gemm1_fused_splitk<<<256, 512, 0, stream>>>(
      feat, W1B, part, BROWS, HIDN, FEATK, FEATK / 4);
  reduce4_bias_relu<<<(BROWS * HIDN / 4 + 255) / 256, 256, 0, stream>>>(
      part, b1, h1, BROWS * HIDN / 4, HIDN / 4);

  // K2: h2 = relu(h1 @ W2^T + b2)  (BM=64 BN=128 -> 512 blocks, counted-vmcnt)
  gemm2_bias_relu<<<dim3(HIDN / K2_BN, BROWS / K2_BM), 256, 0, stream>>>(
      h1, W2B, b2, h2, BROWS, HIDN, HIDN);

  // K3: shared = h2 @ W3^T + b3 ; routed 2x2 affines -> out
  head_kernel<<<(BROWS * 64) / 256, 256, 0, stream>>>(
      h2, W3, b3, sidx, xyW, xyb, tW, out);
}